// Round 16
// baseline (13.845 us; speedup 1.0000x reference)
//
#include <hip/hip_runtime.h>
#include <math.h>

#define NGRID 1000
#define BLOCK 512      // 8 waves: 0-1 = MFMA MLP (16 rows each), all 8 scan 4 rows

typedef __attribute__((ext_vector_type(8))) __bf16 bf16x8;
typedef __attribute__((ext_vector_type(4))) float  f32x4;

__device__ __forceinline__ float frcp(float x)  { return __builtin_amdgcn_rcpf(x); }
__device__ __forceinline__ float fsqrt(float x) { return __builtin_amdgcn_sqrtf(x); }

#define MFMA16(A,Bv,C) __builtin_amdgcn_mfma_f32_16x16x32_bf16((A),(Bv),(C),0,0,0)

// split v into bf16 hi (RTNE cast) + bf16 lo (residual), by value
__device__ __forceinline__ __bf16 bhi(float v) { return (__bf16)v; }
__device__ __forceinline__ __bf16 blo(float v, __bf16 hi) {
    return (__bf16)(v - (float)hi);
}

__global__ __launch_bounds__(BLOCK) void ph_kernel(
    const float* __restrict__ x,
    const float* __restrict__ W1, const float* __restrict__ b1,
    const float* __restrict__ W2, const float* __restrict__ b2,
    const float* __restrict__ W3, const float* __restrict__ b3,
    const float* __restrict__ W4, const float* __restrict__ b4,
    const float* __restrict__ kin,
    float* __restrict__ out, int B)
{
    // weight fragments in MFMA-frag-ready order: [nt][kt][lane][e] -> b128/lane
    __shared__ __attribute__((aligned(16))) __bf16 sW1h[4][64][8],    sW1l[4][64][8];
    __shared__ __attribute__((aligned(16))) __bf16 sW2h[4][2][64][8], sW2l[4][2][64][8];
    __shared__ __attribute__((aligned(16))) __bf16 sW3h[4][2][64][8], sW3l[4][2][64][8];
    __shared__ __attribute__((aligned(16))) __bf16 sW4h[2][64][8],    sW4l[2][64][8];
    // h planes: [block row 0..31][k], stride 72 (144B) kills b128 conflicts
    __shared__ __attribute__((aligned(16))) __bf16 sHh[32][72], sHl[32][72];
    __shared__ float sLat[32][8];
    __shared__ float sPhy[32][6];   // c0,c1,c2,invl0,invl1 per block row
    // Tafel tables (row-independent): sTA = coarse points v=32j (stride-1 by j),
    // sTB = full grid (stride-1 by v) -> both conflict-free for their readers.
    __shared__ float sTA0[32], sTA1[32], sTA2[32];
    __shared__ float sTB0[NGRID], sTB1[NGRID], sTB2[NGRID];

    const int tid  = threadIdx.x;
    const int lane = tid & 63;
    const int widx = tid >> 6;      // 0..7
    const int lr   = lane & 15;     // A-row / B-col / C-col within 16-tile
    const int kg   = lane >> 4;     // k-group (8 k's per group)
    const int br0  = blockIdx.x * 32;              // block's first row

    // ================== hoisted cold loads (issue at top) ==================
    const float i00 = kin[0], i01 = kin[1], i02 = kin[2];
    const float invRT = 1.0f / 2478.8191f;
    const float ksr0 = ((-kin[3]) * 96485.33f) * invRT;
    const float ksr1 = ((-kin[4]) * 96485.33f) * invRT;
    const float ksr2 = ((-kin[5]) * 96485.33f) * invRT;
    const float stepV = 1.25f / 999.0f;

    // physics-row zlt (per-lane; same redundant read physics did before)
    const int lr4 = lr & 3;
    const int brow_me = widx*4 + lr4;
    const int prow_me = (br0 + brow_me < B) ? (br0 + brow_me) : (B - 1);
    const float zlt_pre = x[prow_me*5 + 3];

    // MLP-wave hoists: biases + x fragments
    float b1v[4] = {0,0,0,0}, b2v[4] = {0,0,0,0}, b3v[4] = {0,0,0,0};
    float b4c = 0.0f;
    bf16x8 xh, xl;
    if (widx < 2) {
        #pragma unroll
        for (int nt = 0; nt < 4; ++nt) {
            b1v[nt] = b1[nt*16 + lr];
            b2v[nt] = b2[nt*16 + lr];
            b3v[nt] = b3[nt*16 + lr];
        }
        if (lr < 6) b4c = b4[lr];
        const int r0 = br0 + widx * 16;
        int xrow = r0 + lr; if (xrow > B-1) xrow = B-1;
        #pragma unroll
        for (int e = 0; e < 8; ++e) {
            float v = 0.0f;
            if (kg == 0 && e < 5) v = x[xrow*5 + e];
            const __bf16 hi = bhi(v);
            xh[e] = hi;
            xl[e] = blo(v, hi);
        }
    }

    // ============== stage weight fragments, split across 8 waves ==========
    if (widx < 4) {
        const int nt  = widx;
        const int col = nt*16 + lr;
        bf16x8 h8, l8;
        #pragma unroll
        for (int e = 0; e < 8; ++e) {
            const int k = kg*8 + e;
            float v = 0.0f;
            if (k < 5) v = W1[k*64 + col];
            const __bf16 hi = bhi(v);
            h8[e] = hi;
            l8[e] = blo(v, hi);
        }
        *(bf16x8*)&sW1h[nt][lane][0] = h8;
        *(bf16x8*)&sW1l[nt][lane][0] = l8;

        #pragma unroll
        for (int kt = 0; kt < 2; ++kt) {
            bf16x8 h2, l2;
            #pragma unroll
            for (int e = 0; e < 8; ++e) {
                const int k = kt*32 + kg*8 + e;
                const float v2 = W2[k*64 + col];
                const __bf16 hi2 = bhi(v2);
                h2[e] = hi2; l2[e] = blo(v2, hi2);
            }
            *(bf16x8*)&sW2h[nt][kt][lane][0] = h2;
            *(bf16x8*)&sW2l[nt][kt][lane][0] = l2;
        }
    } else {
        const int nt  = widx - 4;
        const int col = nt*16 + lr;
        #pragma unroll
        for (int kt = 0; kt < 2; ++kt) {
            bf16x8 h3, l3;
            #pragma unroll
            for (int e = 0; e < 8; ++e) {
                const int k = kt*32 + kg*8 + e;
                const float v3 = W3[k*64 + col];
                const __bf16 hi3 = bhi(v3);
                h3[e] = hi3; l3[e] = blo(v3, hi3);
            }
            *(bf16x8*)&sW3h[nt][kt][lane][0] = h3;
            *(bf16x8*)&sW3l[nt][kt][lane][0] = l3;
        }
        if (widx == 4) {                 // W4 (64x6): cols>=6 zero
            #pragma unroll
            for (int kt = 0; kt < 2; ++kt) {
                bf16x8 h4, l4;
                #pragma unroll
                for (int e = 0; e < 8; ++e) {
                    const int k = kt*32 + kg*8 + e;
                    float v = 0.0f;
                    if (lr < 6) v = W4[k*6 + lr];
                    const __bf16 hi = bhi(v);
                    h4[e] = hi;
                    l4[e] = blo(v, hi);
                }
                *(bf16x8*)&sW4h[kt][lane][0] = h4;
                *(bf16x8*)&sW4l[kt][lane][0] = l4;
            }
        }
    }

    // ==== Tafel tables: waves 2-7 build while waves 0-1 head to the MLP ====
    // (same fp expressions as the old in-scan exps -> bitwise identical)
    if (widx >= 2) {
        for (int v = (widx-2)*64 + lane; v < NGRID; v += 384) {
            const float V = -1.25f + stepV * (float)v;
            const float t0 = __expf(ksr0 * (V + 0.11f));
            const float t1 = __expf(ksr1 * (V - 0.08f));
            const float t2 = __expf(ksr2 * V);
            sTB0[v] = t0; sTB1[v] = t1; sTB2[v] = t2;
            if ((v & 31) == 0) {
                const int jj = v >> 5;
                sTA0[jj] = t0; sTA1[jj] = t1; sTA2[jj] = t2;
            }
        }
    }
    __syncthreads();   // barrier 1: weights staged (tables done by barrier 2)

    // ================= MLP on waves 0-1 (R12-verbatim tiling) =============
    if (widx < 2) {
        const f32x4 zz = {0.0f, 0.0f, 0.0f, 0.0f};
        f32x4 acc[4];

        // ---- layer 1: x(16x5 pad32) @ W1 ----
        #pragma unroll
        for (int nt = 0; nt < 4; ++nt) {
            const bf16x8 bh = *(const bf16x8*)&sW1h[nt][lane][0];
            const bf16x8 bl = *(const bf16x8*)&sW1l[nt][lane][0];
            f32x4 t = MFMA16(xl, bh, zz);
            t = MFMA16(xh, bl, t);
            acc[nt] = MFMA16(xh, bh, t);
        }
        #pragma unroll
        for (int nt = 0; nt < 4; ++nt) {
            const float bb = b1v[nt];
            #pragma unroll
            for (int rg = 0; rg < 4; ++rg) {
                float v = fmaxf(acc[nt][rg] + bb, 0.0f);
                const int row = widx*16 + kg*4 + rg;
                const __bf16 hi = bhi(v);
                sHh[row][nt*16 + lr] = hi;
                sHl[row][nt*16 + lr] = blo(v, hi);
            }
        }

        // ---- layers 2,3: h(16x64) @ W ----
        #pragma unroll
        for (int L = 0; L < 2; ++L) {
            const int lrow = widx*16 + lr;
            bf16x8 ah[2], al[2];
            #pragma unroll
            for (int kt = 0; kt < 2; ++kt) {
                ah[kt] = *(const bf16x8*)&sHh[lrow][kt*32 + kg*8];
                al[kt] = *(const bf16x8*)&sHl[lrow][kt*32 + kg*8];
            }
            #pragma unroll
            for (int nt = 0; nt < 4; ++nt) {
                f32x4 t = zz;
                #pragma unroll
                for (int kt = 0; kt < 2; ++kt) {
                    const bf16x8 bh = (L == 0) ? *(const bf16x8*)&sW2h[nt][kt][lane][0]
                                               : *(const bf16x8*)&sW3h[nt][kt][lane][0];
                    const bf16x8 bl = (L == 0) ? *(const bf16x8*)&sW2l[nt][kt][lane][0]
                                               : *(const bf16x8*)&sW3l[nt][kt][lane][0];
                    t = MFMA16(al[kt], bh, t);
                    t = MFMA16(ah[kt], bl, t);
                    t = MFMA16(ah[kt], bh, t);
                }
                acc[nt] = t;
            }
            #pragma unroll
            for (int nt = 0; nt < 4; ++nt) {
                const float bb = (L == 0) ? b2v[nt] : b3v[nt];
                #pragma unroll
                for (int rg = 0; rg < 4; ++rg) {
                    float v = fmaxf(acc[nt][rg] + bb, 0.0f);
                    const int row = widx*16 + kg*4 + rg;
                    const __bf16 hi = bhi(v);
                    sHh[row][nt*16 + lr] = hi;   // in-place: reads already done
                    sHl[row][nt*16 + lr] = blo(v, hi);
                }
            }
        }

        // ---- layer 4: h(16x64) @ W4 -> sLat ----
        {
            const int lrow = widx*16 + lr;
            f32x4 t = zz;
            #pragma unroll
            for (int kt = 0; kt < 2; ++kt) {
                const bf16x8 ah = *(const bf16x8*)&sHh[lrow][kt*32 + kg*8];
                const bf16x8 al = *(const bf16x8*)&sHl[lrow][kt*32 + kg*8];
                const bf16x8 bh = *(const bf16x8*)&sW4h[kt][lane][0];
                const bf16x8 bl = *(const bf16x8*)&sW4l[kt][lane][0];
                t = MFMA16(al, bh, t);
                t = MFMA16(ah, bl, t);
                t = MFMA16(ah, bh, t);
            }
            if (lr < 6) {
                #pragma unroll
                for (int rg = 0; rg < 4; ++rg)
                    sLat[widx*16 + kg*4 + rg][lr] = t[rg] + b4c;
            }
        }
    }
    __syncthreads();   // barrier 2: latents + tables ready for all 8 waves

    // ======== physics: all 8 waves, wave w owns block rows w*4..w*4+3 ======
    {
        const int brow = brow_me;                      // block row 0..31
        const float* plat = &sLat[brow][0];
        const float lat0 = plat[0], lat1 = plat[1], lat2 = plat[2];
        const float lat3 = plat[3], lat4 = plat[4], lat5 = plat[5];
        const float rrad = 4e-8f * __expf(lat0);
        const float epsv = frcp(1.0f + __expf(-lat1));
        const float zlt  = zlt_pre;
        const float Lf   = zlt * frcp(1.0f - epsv);
        const float Kdl  = __expf(lat2);
        const float z0 = 2.0f*lat3, z1 = 2.0f*lat4, z2 = 2.0f*lat5;
        const float mz = fmaxf(z0, fmaxf(z1, z2));
        const float p0 = __expf(z0 - mz), p1 = __expf(z1 - mz), p2 = __expf(z2 - mz);
        const float ips = frcp(p0 + p1 + p2);
        const float th0 = p0*ips, th1 = p1*ips, th2 = p2*ips;
        const float irr = frcp(rrad);
        const float gdl   = (Kdl * 1.91e-9f) * (epsv * fsqrt(epsv)) * irr;
        const float asurf = (3.0f * (1.0f - epsv)) * Lf * irr;
        const float c0v = (i00*th0)*asurf;
        const float c1v = (i01*th1)*asurf;
        const float c2v = (i02*th2)*asurf;
        const float il0 = (((2.0f*96485.33f)*34.0f)*gdl)*0.1f;
        const float il1 = (((12.0f*96485.33f)*34.0f)*gdl)*0.1f;
        if (kg == 0 && lr < 4) {
            sPhy[brow][0] = c0v;
            sPhy[brow][1] = c1v;
            sPhy[brow][2] = c2v;
            sPhy[brow][3] = frcp(il0);
            sPhy[brow][4] = frcp(il1);
        }
    }
    // wave-local write -> read (each wave reads only its own 4 rows)

    // ================= scan: 2 passes x 2 rows per wave =================
    const int half = lane >> 5;
    const int la   = lane & 31;

    #pragma unroll 1
    for (int p = 0; p < 2; ++p) {
        const int brow = widx*4 + p*2 + half;  // block row 0..31
        const int row  = br0 + brow;
        const bool act = (row < B);

        const float c0    = sPhy[brow][0];
        const float c1    = sPhy[brow][1];
        const float c2    = sPhy[brow][2];
        const float invl0 = sPhy[brow][3];
        const float invl1 = sPhy[brow][4];

        // coarse: v = la*32, tafel from sTA (stride-1, conflict-free)
        const int vc = la << 5;
        float totc;
        {
            const float t0 = sTA0[la], t1 = sTA1[la], t2 = sTA2[la];
            const float ie0 = frcp(frcp(c0*t0) + invl0);
            const float ie1 = frcp(frcp(c1*t1) + invl1);
            const float ie2 = c2*t2;       // i_lim[2] = inf
            totc = ie0 + ie1 + ie2;
        }
        float bd = fabsf(totc - 200.0f);
        int bidx = vc;

        const unsigned long long mall = __ballot(totc >= 200.0f);
        const unsigned int m32 = (unsigned int)(mall >> (half << 5));
        const int kstar = m32 ? (31 - __builtin_clz(m32)) : 0;
        const int base = kstar << 5;

        // fine: 32 consecutive points (base, base+32], tafel from sTB
        {
            int vf = base + 1 + la;
            if (vf > NGRID-1) vf = NGRID-1;
            const float t0 = sTB0[vf], t1 = sTB1[vf], t2 = sTB2[vf];
            const float ie0 = frcp(frcp(c0*t0) + invl0);
            const float ie1 = frcp(frcp(c1*t1) + invl1);
            const float ie2 = c2*t2;
            const float totf = ie0 + ie1 + ie2;
            const float df = fabsf(totf - 200.0f);
            if (df < bd || (df == bd && vf < bidx)) { bd = df; bidx = vf; }
        }

        // lexicographic (d, idx) butterfly within each 32-lane half
        #pragma unroll
        for (int off = 16; off; off >>= 1) {
            const float od = __shfl_xor(bd, off, 64);
            const int   oi = __shfl_xor(bidx, off, 64);
            if (od < bd || (od == bd && oi < bidx)) { bd = od; bidx = oi; }
        }

        // ---- select + FE (tafel from sTB, uniform per half -> broadcast) ----
        const float t0 = sTB0[bidx], t1 = sTB1[bidx], t2 = sTB2[bidx];
        const float ie0 = frcp(frcp(c0*t0) + invl0);
        const float ie1 = frcp(frcp(c1*t1) + invl1);
        const float ie2 = c2*t2;
        const float itr = frcp(ie0 + ie1 + ie2);
        if (act && la < 2) {
            out[row*2 + la] = (la == 0) ? (ie1*itr) : (ie0*itr);
        }
    }
}

extern "C" void kernel_launch(void* const* d_in, const int* in_sizes, int n_in,
                              void* d_out, int out_size, void* d_ws, size_t ws_size,
                              hipStream_t stream) {
    const float* x   = (const float*)d_in[0];
    const float* W1  = (const float*)d_in[1];
    const float* b1  = (const float*)d_in[2];
    const float* W2  = (const float*)d_in[3];
    const float* b2  = (const float*)d_in[4];
    const float* W3  = (const float*)d_in[5];
    const float* b3  = (const float*)d_in[6];
    const float* W4  = (const float*)d_in[7];
    const float* b4  = (const float*)d_in[8];
    const float* kin = (const float*)d_in[9];
    float* out = (float*)d_out;
    const int B = in_sizes[0] / 5;

    // 32 rows per block, 8 waves: waves 0-1 MFMA-MLP (R12 tiling verbatim),
    // waves 2-7 build shared Tafel tables during the MLP window,
    // all 8 waves split physics+scan (4 rows each, 2 passes).
    // 512 blocks x ~67 KB LDS = 2 resident blocks/CU = 4 waves/SIMD.
    const int grid = (B + 31) / 32;
    ph_kernel<<<grid, BLOCK, 0, stream>>>(x, W1, b1, W2, b2, W3, b3, W4, b4, kin, out, B);
}